// Round 19
// baseline (117.500 us; speedup 1.0000x reference)
//
#include <hip/hip_runtime.h>
#include <hip/hip_bf16.h>

#define B 16
#define T 128
#define D 256
#define H 64
#define C1 64
#define C2 20
#define K2 4096   // H*C1
#define F2 1280   // H*C2
#define OUTW 32
#define ALPHA 0.2f

typedef __attribute__((ext_vector_type(8))) short short8;
typedef __attribute__((ext_vector_type(4))) float f32x4;

static __device__ __forceinline__ ushort f2bf(float f) {
    __hip_bfloat16 h = __float2bfloat16(f);
    return *reinterpret_cast<ushort*>(&h);
}
static __device__ __forceinline__ float bf2f(ushort u) {
    return __uint_as_float(((unsigned int)u) << 16);
}
// async global->LDS, 16B per lane; LDS dest is wave-uniform base + lane*16.
static __device__ __forceinline__ void gload16(const ushort* g, ushort* l) {
    __builtin_amdgcn_global_load_lds((const unsigned int*)g, (unsigned int*)l,
                                     16, 0, 0);
}

// ---------------------------------------------------------------------------
// Split-K MFMA GEMM (verified round 8) + PERM epilogue (verified round 11).
// KSPLIT must divide KD/64 (KDP multiple of 64) — enforced below.
// ---------------------------------------------------------------------------
template<int KD, int NBLK, int MBLK, int KSPLIT, int PERM>
__global__ __launch_bounds__(256) void gemm_splitk_kernel(
    const ushort* __restrict__ Ag, const ushort* __restrict__ Bg,
    ushort* __restrict__ Cp)
{
    __shared__ ushort As[128 * 64];
    __shared__ ushort Bs[128 * 64];
    constexpr int NN = NBLK * 128;
    constexpr int MM = MBLK * 128;
    constexpr int NT = MBLK * NBLK;
    constexpr int TOTAL = NT * KSPLIT;
    constexpr int KDP = KD / KSPLIT;
    static_assert(TOTAL % 8 == 0, "swizzle needs multiple of 8 blocks");
    static_assert(KDP % 64 == 0, "K partition must be a multiple of BK=64");

    int tid = threadIdx.x;
    int bid = blockIdx.x;
    int wg = (bid & 7) * (TOTAL / 8) + (bid >> 3);
    int kp = wg / NT; int tile = wg - kp * NT;
    int bm = (tile / NBLK) * 128, bn = (tile % NBLK) * 128;

    int wave = tid >> 6, lane = tid & 63;
    int wm = (wave >> 1) * 64, wn = (wave & 1) * 64;
    int lr = lane & 15, lk = lane >> 4;
    int srow = lane >> 3, scol = (lane & 7) * 8;

    f32x4 acc[4][4];
    #pragma unroll
    for (int i = 0; i < 4; ++i)
        #pragma unroll
        for (int j = 0; j < 4; ++j) acc[i][j] = (f32x4){0.f, 0.f, 0.f, 0.f};

    const ushort* ApB = Ag + (size_t)bm * KD + kp * KDP;
    const ushort* BpB = Bg + (size_t)bn * KD + kp * KDP;

    for (int k0 = 0; k0 < KDP; k0 += 64) {
        __syncthreads();
        #pragma unroll
        for (int e = 0; e < 4; ++e) {
            int c = e * 4 + wave;
            gload16(ApB + (size_t)(8 * c + srow) * KD + k0 + scol, &As[c * 512]);
            gload16(BpB + (size_t)(8 * c + srow) * KD + k0 + scol, &Bs[c * 512]);
        }
        __syncthreads();
        #pragma unroll
        for (int ks = 0; ks < 2; ++ks) {
            short8 af[4], bfr[4];
            #pragma unroll
            for (int i = 0; i < 4; ++i)
                af[i] = *(const short8*)&As[(wm + i * 16 + lr) * 64 + ks * 32 + lk * 8];
            #pragma unroll
            for (int j = 0; j < 4; ++j)
                bfr[j] = *(const short8*)&Bs[(wn + j * 16 + lr) * 64 + ks * 32 + lk * 8];
            #pragma unroll
            for (int i = 0; i < 4; ++i)
                #pragma unroll
                for (int j = 0; j < 4; ++j)
                    acc[i][j] = __builtin_amdgcn_mfma_f32_16x16x32_bf16(
                        af[i], bfr[j], acc[i][j], 0, 0, 0);
        }
    }

    if constexpr (PERM) {
        ushort* Cw = Cp + (size_t)kp * MM * NN + (size_t)tile * 16384
                   + wave * 4096 + lane * 4;
        #pragma unroll
        for (int i = 0; i < 4; ++i)
            #pragma unroll
            for (int j = 0; j < 4; ++j) {
                union { ushort q[4]; uint2 v; } pk;
                #pragma unroll
                for (int r = 0; r < 4; ++r) pk.q[r] = f2bf(acc[i][j][r]);
                *(uint2*)&Cw[(i * 4 + j) * 256] = pk.v;
            }
    } else {
        ushort* Cout = Cp + (size_t)kp * MM * NN;
        #pragma unroll
        for (int i = 0; i < 4; ++i) {
            #pragma unroll
            for (int j = 0; j < 4; ++j) {
                int col = bn + wn + j * 16 + lr;
                #pragma unroll
                for (int r = 0; r < 4; ++r) {
                    int row = bm + wm + i * 16 + lk * 4 + r;
                    Cout[(size_t)row * NN + col] = f2bf(acc[i][j][r]);
                }
            }
        }
    }
}

// ---------------------------------------------------------------------------
// FUSED kernel 1 v4 (verified round 16): wave owns 32 unique rows x 64 cols.
// ---------------------------------------------------------------------------
#define WHT_(r,c) whT[(r) * 136 + (c)]

__global__ __launch_bounds__(256) void fused1_kernel(
    const ushort* __restrict__ xbf,   // [B*T][256] bf16
    const ushort* __restrict__ w1t,   // [H*64][256] bf16
    const float* __restrict__ b1,     // [4096] ([h][c] flat)
    const float* __restrict__ a1s, const float* __restrict__ a1d,
    const float* __restrict__ a1b,
    ushort* __restrict__ c1)          // [B*T][4096] row-major
{
    int blk = blockIdx.x; int b = blk >> 6, h = blk & 63;
    __shared__ ushort whT[64 * 136];
    __shared__ ushort CT[128 * 72];
    __shared__ float ss[128], ddv[128], sinv[128];

    int tid = threadIdx.x;
    int wave = tid >> 6, lane = tid & 63;
    int wm2 = wave * 32;
    int lr = lane & 15, lk = lane >> 4;

    // ---- phase A: Wh1 = x @ w1t^T, fragment-direct global loads ----
    f32x4 acc[2][4];
    #pragma unroll
    for (int i = 0; i < 2; ++i)
        #pragma unroll
        for (int j = 0; j < 4; ++j) acc[i][j] = (f32x4){0.f, 0.f, 0.f, 0.f};

    const ushort* Abase = xbf + (size_t)(b * T + wm2 + lr) * D + lk * 8;
    const ushort* Bbase = w1t + (size_t)(h * 64 + lr) * D + lk * 8;

    #pragma unroll 2
    for (int kb = 0; kb < 8; ++kb) {
        short8 af[2], bfr[4];
        #pragma unroll
        for (int i = 0; i < 2; ++i)
            af[i] = *(const short8*)(Abase + (size_t)i * 16 * D + kb * 32);
        #pragma unroll
        for (int j = 0; j < 4; ++j)
            bfr[j] = *(const short8*)(Bbase + (size_t)j * 16 * D + kb * 32);
        #pragma unroll
        for (int i = 0; i < 2; ++i)
            #pragma unroll
            for (int j = 0; j < 4; ++j)
                acc[i][j] = __builtin_amdgcn_mfma_f32_16x16x32_bf16(
                    af[i], bfr[j], acc[i][j], 0, 0, 0);
    }

    // epilogue: whT[col][t] = bf16(Wh + bias)
    #pragma unroll
    for (int j = 0; j < 4; ++j) {
        int col = j * 16 + lr;
        float bv = b1[h * C1 + col];
        #pragma unroll
        for (int i = 0; i < 2; ++i) {
            int t0 = wm2 + i * 16 + lk * 4;
            union { ushort q[4]; uint2 v; } pk;
            #pragma unroll
            for (int r = 0; r < 4; ++r) pk.q[r] = f2bf(acc[i][j][r] + bv);
            *(uint2*)&WHT_(col, t0) = pk.v;
        }
    }
    __syncthreads();                                   // barrier 1

    // ---- phase B: scores ----
    {
        int t = tid & 127;
        bool isS = tid < 128;
        const float* av = (isS ? a1s : a1d) + h * C1;
        float s = isS ? a1b[h] : 0.f;
        #pragma unroll 8
        for (int c = 0; c < 64; ++c) s = fmaf(bf2f(WHT_(c, t)), av[c], s);
        if (isS) ss[t] = s; else ddv[t] = s;
    }
    __syncthreads();                                   // barrier 2

    // ---- phase C'+D: P~ in-register + PV MFMA ----
    float dm = fmaxf(ddv[lane], ddv[lane + 64]);
    #pragma unroll
    for (int msk = 1; msk < 64; msk <<= 1) dm = fmaxf(dm, __shfl_xor(dm, msk));

    float si[2], mi[2], rsum[2];
    #pragma unroll
    for (int i = 0; i < 2; ++i) {
        si[i] = ss[wm2 + i * 16 + lr];
        float mx = si[i] + dm;
        mi[i] = mx >= 0.f ? mx : ALPHA * mx;
        rsum[i] = 0.f;
    }

    f32x4 acc2[2][4];
    #pragma unroll
    for (int i = 0; i < 2; ++i)
        #pragma unroll
        for (int j = 0; j < 4; ++j) acc2[i][j] = (f32x4){0.f, 0.f, 0.f, 0.f};

    #pragma unroll
    for (int ks = 0; ks < 4; ++ks) {
        float dj[8];
        #pragma unroll
        for (int e = 0; e < 8; ++e) dj[e] = ddv[ks * 32 + lk * 8 + e];
        short8 bfr[4];
        #pragma unroll
        for (int j = 0; j < 4; ++j)
            bfr[j] = *(const short8*)&WHT_(j * 16 + lr, ks * 32 + lk * 8);
        #pragma unroll
        for (int i = 0; i < 2; ++i) {
            union { ushort q[8]; short8 s; } pk;
            #pragma unroll
            for (int e = 0; e < 8; ++e) {
                float ee = si[i] + dj[e];
                ee = ee >= 0.f ? ee : ALPHA * ee;
                float pp = __expf(ee - mi[i]);
                rsum[i] += pp;
                pk.q[e] = f2bf(pp);
            }
            #pragma unroll
            for (int j = 0; j < 4; ++j)
                acc2[i][j] = __builtin_amdgcn_mfma_f32_16x16x32_bf16(
                    pk.s, bfr[j], acc2[i][j], 0, 0, 0);
        }
    }

    #pragma unroll
    for (int i = 0; i < 2; ++i) {
        rsum[i] += __shfl_xor(rsum[i], 16);
        rsum[i] += __shfl_xor(rsum[i], 32);
    }
    if (lk == 0) {
        #pragma unroll
        for (int i = 0; i < 2; ++i) sinv[wm2 + i * 16 + lr] = 1.0f / rsum[i];
    }
    __syncthreads();                                   // barrier 3

    // ---- epilogue: CT restage, then coalesced uint4 rows ----
    #pragma unroll
    for (int i = 0; i < 2; ++i) {
        #pragma unroll
        for (int r = 0; r < 4; ++r) {
            int row = wm2 + i * 16 + lk * 4 + r;
            float sv = sinv[row];
            #pragma unroll
            for (int j = 0; j < 4; ++j) {
                int col = j * 16 + lr;
                float v = acc2[i][j][r] * sv;
                v = v > 0.f ? v : 0.f;
                v = 1.0f / (1.0f + __expf(-v));
                CT[row * 72 + col] = f2bf(v);
            }
        }
    }
    __syncthreads();                                   // barrier 4
    #pragma unroll
    for (int e = 0; e < 4; ++e) {
        int idx = e * 256 + tid;           // 0..1023: row = idx>>3, q = idx&7
        int row = idx >> 3, q = idx & 7;
        uint4 v = *(const uint4*)&CT[row * 72 + q * 8];
        *(uint4*)&c1[((size_t)(b * T + row)) * K2 + h * C1 + q * 8] = v;
    }
}

// ---------------------------------------------------------------------------
// FUSED kernel 2 v3 (KSPLIT=4 gather): vectorized split-K gather -> scores
// -> P~ -> PV MFMA -> coalesced c2 write.
// ---------------------------------------------------------------------------
#define PB2_(r,c)  Pb2[(r) * 136 + (c)]
#define WHT2_(r,c) whT2[(r) * 136 + (c)]

__global__ __launch_bounds__(256) void fused2_kernel(
    const ushort* __restrict__ wh2pb,  // [4] x permuted [2048][1280] bf16
    const float* __restrict__ b2,      // [1280] ([h][c] flat)
    const float* __restrict__ a2s, const float* __restrict__ a2d,
    const float* __restrict__ a2b,
    ushort* __restrict__ c2)
{
    int blk = blockIdx.x; int b = blk >> 6, h = blk & 63;
    __shared__ ushort Pb2[128 * 136];
    __shared__ ushort whT2[32 * 136];
    __shared__ float ss[128], ddv[128], sinv[128];

    int tid = threadIdx.x;
    int wave = tid >> 6, lane = tid & 63;
    int lr = lane & 15, lk = lane >> 4;
    const size_t MNfull = (size_t)2048 * F2;

    // ---- load + split-K reduce: 640 (t-quad, c) tasks, uint2 per partial ----
    for (int e = 0; e < 3; ++e) {
        int idx = e * 256 + tid;
        if (idx < 640) {
            int tq = idx / 20, c = idx - tq * 20;
            int col = h * C2 + c;
            int tn = col >> 7, cl = col & 127;
            int fj = (cl >> 4) & 3, fl = cl & 15;
            int t0 = tq * 4;
            int wv = ((t0 >> 6) << 1) | (cl >> 6);
            int fi = (t0 >> 4) & 3, fk = (t0 >> 2) & 3;
            size_t fa = (size_t)(b * 10 + tn) * 16384 + wv * 4096
                      + (fi * 4 + fj) * 256 + (fk * 16 + fl) * 4;
            float bv = b2[col];
            float s0 = bv, s1 = bv, s2 = bv, s3 = bv;
            #pragma unroll
            for (int p = 0; p < 4; ++p) {
                uint2 v = *(const uint2*)&wh2pb[p * MNfull + fa];
                s0 += bf2f((ushort)(v.x & 0xffff));
                s1 += bf2f((ushort)(v.x >> 16));
                s2 += bf2f((ushort)(v.y & 0xffff));
                s3 += bf2f((ushort)(v.y >> 16));
            }
            union { ushort q[4]; uint2 u; } o;
            o.q[0] = f2bf(s0); o.q[1] = f2bf(s1);
            o.q[2] = f2bf(s2); o.q[3] = f2bf(s3);
            *(uint2*)&WHT2_(c, t0) = o.u;
        }
    }
    {   // zero-pad rows 20..31
        int idx = tid;
        for (int e = 0; e < 6; ++e, idx += 256) {
            int c = 20 + (idx >> 7), t = idx & 127;
            WHT2_(c, t) = 0;
        }
    }
    __syncthreads();

    // ---- scores ----
    {
        int t = tid & 127;
        bool isS = tid < 128;
        const float* av = (isS ? a2s : a2d) + h * C2;
        float s = isS ? a2b[h] : 0.f;
        #pragma unroll
        for (int c = 0; c < 20; ++c) s = fmaf(bf2f(WHT2_(c, t)), av[c], s);
        if (isS) ss[t] = s; else ddv[t] = s;
    }
    __syncthreads();

    // ---- P~ + row sums ----
    {
        float dm = fmaxf(ddv[lane], ddv[lane + 64]);
        #pragma unroll
        for (int msk = 1; msk < 64; msk <<= 1) dm = fmaxf(dm, __shfl_xor(dm, msk));
        int i = tid >> 1, j0 = (tid & 1) * 64;
        float si = ss[i];
        float mx = si + dm; mx = mx >= 0.f ? mx : ALPHA * mx;
        float lsum = 0.f;
        #pragma unroll
        for (int g = 0; g < 8; ++g) {
            union { ushort q[8]; uint4 v; } pk;
            #pragma unroll
            for (int e = 0; e < 8; ++e) {
                float ee = si + ddv[j0 + g * 8 + e];
                ee = ee >= 0.f ? ee : ALPHA * ee;
                float pp = __expf(ee - mx);
                lsum += pp;
                pk.q[e] = f2bf(pp);
            }
            *(uint4*)&PB2_(i, j0 + g * 8) = pk.v;
        }
        lsum += __shfl_xor(lsum, 1);
        if (!(tid & 1)) sinv[i] = 1.0f / lsum;
    }
    __syncthreads();

    // ---- PV: out[128][32] = P~ @ whT2^T; wave owns 32 rows ----
    int wm2 = wave * 32;
    f32x4 acc2[2][2];
    #pragma unroll
    for (int i = 0; i < 2; ++i)
        #pragma unroll
        for (int j = 0; j < 2; ++j) acc2[i][j] = (f32x4){0.f, 0.f, 0.f, 0.f};

    #pragma unroll
    for (int ks = 0; ks < 4; ++ks) {
        short8 af[2], bfr[2];
        #pragma unroll
        for (int i = 0; i < 2; ++i)
            af[i] = *(const short8*)&PB2_(wm2 + i * 16 + lr, ks * 32 + lk * 8);
        #pragma unroll
        for (int j = 0; j < 2; ++j)
            bfr[j] = *(const short8*)&WHT2_(j * 16 + lr, ks * 32 + lk * 8);
        #pragma unroll
        for (int i = 0; i < 2; ++i)
            #pragma unroll
            for (int j = 0; j < 2; ++j)
                acc2[i][j] = __builtin_amdgcn_mfma_f32_16x16x32_bf16(
                    af[i], bfr[j], acc2[i][j], 0, 0, 0);
    }

    // ---- coalesced epilogue via LDS restage (reuse Pb2) ----
    __syncthreads();
    ushort* CT2 = Pb2;                     // [128][24]
    #pragma unroll
    for (int i = 0; i < 2; ++i) {
        #pragma unroll
        for (int r = 0; r < 4; ++r) {
            int row = wm2 + i * 16 + lk * 4 + r;
            float sv = sinv[row];
            #pragma unroll
            for (int j = 0; j < 2; ++j) {
                int col = j * 16 + lr;
                if (col < C2) {
                    float v = acc2[i][j][r] * sv;
                    v = v > 0.f ? v : 0.f;
                    v = 1.0f / (1.0f + __expf(-v));
                    CT2[row * 24 + col] = f2bf(v);
                }
            }
        }
    }
    __syncthreads();
    for (int e = 0; e < 3; ++e) {
        int idx = e * 256 + tid;           // 0..639: row = idx/5, q = idx%5
        if (idx < 640) {
            int row = idx / 5, q = idx - row * 5;
            uint2 v = *(const uint2*)&CT2[row * 24 + q * 4];
            *(uint2*)&c2[((size_t)(b * T + row)) * F2 + h * C2 + q * 4] = v;
        }
    }
}

// ---------------------------------------------------------------------------
// MERGED prep kernel (verified round 17).
// ---------------------------------------------------------------------------
__global__ __launch_bounds__(256) void prep_kernel(
    const float* __restrict__ x,  const float* __restrict__ W1,
    const float* __restrict__ W2, const float* __restrict__ slw,
    ushort* __restrict__ xbf, ushort* __restrict__ w1t,
    ushort* __restrict__ w2t, ushort* __restrict__ slwt)
{
    __shared__ union { float a[64][65]; float b[128][21]; } lw;
    int bid = blockIdx.x, tid = threadIdx.x;

    if (bid < 512) {                       // ---- xbf ----
        int i = bid * 256 + tid;
        float4 v = *(const float4*)&x[(size_t)i * 4];
        union { ushort u[4]; uint2 p; } o;
        o.u[0] = f2bf(v.x); o.u[1] = f2bf(v.y);
        o.u[2] = f2bf(v.z); o.u[3] = f2bf(v.w);
        *(uint2*)&xbf[(size_t)i * 4] = o.p;
    } else if (bid < 768) {                // ---- w1t ----
        int blk = bid - 512; int h = blk >> 2, d0 = (blk & 3) * 64;
        for (int e = 0; e < 16; ++e) {
            int idx = e * 256 + tid; int dr = idx >> 6, c = idx & 63;
            lw.a[dr][c] = W1[((size_t)h * D + d0 + dr) * C1 + c];
        }
        __syncthreads();
        for (int e = 0; e < 16; ++e) {
            int idx = e * 256 + tid; int c = idx >> 6, dr = idx & 63;
            w1t[((size_t)(h * 64 + c)) * D + d0 + dr] = f2bf(lw.a[dr][c]);
        }
    } else if (bid < 2816) {               // ---- w2t ----
        int blk = bid - 768; int h = blk >> 5, kb = blk & 31; int k0 = kb * 128;
        const float* src = W2 + ((size_t)h * K2 + k0) * C2;
        for (int e = 0; e < 10; ++e) {
            int idx = e * 256 + tid; int k = idx / 20, c = idx - k * 20;
            lw.b[k][c] = src[idx];
        }
        __syncthreads();
        for (int e = 0; e < 10; ++e) {
            int idx = e * 256 + tid; int c = idx >> 7, k = idx & 127;
            w2t[((size_t)(h * 20 + c)) * K2 + k0 + k] = f2bf(lw.b[k][c]);
        }
    } else {                               // ---- slwt ----
        int blk = bid - 2816; int kb = blk >> 2, d0 = (blk & 3) * 64;
        int k0 = kb * 64;
        for (int e = 0; e < 16; ++e) {
            int idx = e * 256 + tid; int kr = idx >> 6, dc = idx & 63;
            lw.a[kr][dc] = slw[((size_t)(k0 + kr)) * D + d0 + dc];
        }
        __syncthreads();
        for (int e = 0; e < 16; ++e) {
            int idx = e * 256 + tid; int dr = idx >> 6, kc = idx & 63;
            slwt[((size_t)(d0 + dr)) * F2 + k0 + kc] = f2bf(lw.a[kc][dr]);
        }
    }
}

// ---------------------------------------------------------------------------
// MERGED gar2 (verified round 17), reducing 10 sl-partials (KSPLIT=10).
// ---------------------------------------------------------------------------
__global__ __launch_bounds__(256) void gar2_kernel(
    const ushort* __restrict__ c3pb,   // [10][2048][256] bf16 partials
    const float* __restrict__ slb, const float* __restrict__ garw,
    const float* __restrict__ garb, float* __restrict__ out)
{
    int blk = blockIdx.x; int b = blk >> 2, dt = (blk & 3) * 64;
    __shared__ float cs[128][65];
    __shared__ float gw[128][32];
    int tid = threadIdx.x;

    for (int e = 0; e < 32; ++e) {
        int idx = e * 256 + tid;
        int t = idx >> 6, d = idx & 63;
        size_t off = (size_t)(b * T + t) * D + dt + d;
        float s = slb[dt + d];
        #pragma unroll
        for (int p = 0; p < 10; ++p)
            s += bf2f(c3pb[(size_t)p * 2048 * 256 + off]);
        cs[t][d] = s;
    }
    for (int e = 0; e < 16; ++e) {
        int idx = e * 256 + tid;
        int t = idx >> 5, o = idx & 31;
        gw[t][o] = garw[t * OUTW + o];
    }
    __syncthreads();

    int d = tid & 63, o0 = (tid >> 6) * 8;
    float accv[8];
    #pragma unroll
    for (int q = 0; q < 8; ++q) accv[q] = garb[o0 + q];
    for (int t = 0; t < T; ++t) {
        float cv = cs[t][d];
        #pragma unroll
        for (int q = 0; q < 8; ++q) accv[q] = fmaf(cv, gw[t][o0 + q], accv[q]);
    }
    #pragma unroll
    for (int q = 0; q < 8; ++q)
        out[((size_t)b * OUTW + o0 + q) * D + dt + d] = accv[q];
}

// ---------------------------------------------------------------------------
extern "C" void kernel_launch(void* const* d_in, const int* in_sizes, int n_in,
                              void* d_out, int out_size, void* d_ws, size_t ws_size,
                              hipStream_t stream) {
    const float* x    = (const float*)d_in[0];
    const float* W1   = (const float*)d_in[1];
    const float* b1   = (const float*)d_in[2];
    const float* a1s  = (const float*)d_in[3];
    const float* a1d  = (const float*)d_in[4];
    const float* a1b  = (const float*)d_in[5];
    const float* W2   = (const float*)d_in[6];
    const float* b2   = (const float*)d_in[7];
    const float* a2s  = (const float*)d_in[8];
    const float* a2d  = (const float*)d_in[9];
    const float* a2b  = (const float*)d_in[10];
    const float* slw  = (const float*)d_in[11];
    const float* slb  = (const float*)d_in[12];
    const float* garw = (const float*)d_in[13];
    const float* garb = (const float*)d_in[14];

    char* p = (char*)d_ws;
    ushort* xbf   = (ushort*)p;  p += (size_t)2048 * 256  * 2;     //  1.0 MB
    ushort* w1t   = (ushort*)p;  p += (size_t)4096 * 256  * 2;     //  2.1 MB
    ushort* c1bf  = (ushort*)p;  p += (size_t)2048 * 4096 * 2;     // 16.8 MB
    ushort* w2t   = (ushort*)p;  p += (size_t)1280 * 4096 * 2;     // 10.5 MB
    ushort* c2bf  = (ushort*)p;  p += (size_t)2048 * 1280 * 2;     //  5.2 MB
    ushort* slwt  = (ushort*)p;  p += (size_t)256  * 1280 * 2;     //  0.7 MB
    ushort* wh2pb = (ushort*)p;  p += (size_t)4 * 2048 * 1280 * 2; // 21 MB
    ushort* c3pb  = (ushort*)c1bf;   // aliases c1bf (dead after gemm2 reads it)
    // c3pb needs 10*2048*256*2 = 10.5 MB <= c1bf's 16.8 MB ✓

    prep_kernel<<<2896, 256, 0, stream>>>(x, W1, W2, slw, xbf, w1t, w2t, slwt);

    fused1_kernel<<<B * H, 256, 0, stream>>>(xbf, w1t, b1, a1s, a1d, a1b, c1bf);

    gemm_splitk_kernel<4096, 10, 16, 4, 1><<<640, 256, 0, stream>>>(c1bf, w2t,
                                                                    wh2pb);
    fused2_kernel<<<B * H, 256, 0, stream>>>(wh2pb, b2, a2s, a2d, a2b, c2bf);

    gemm_splitk_kernel<1280, 2, 16, 10, 0><<<320, 256, 0, stream>>>(c2bf, slwt,
                                                                    c3pb);
    gar2_kernel<<<B * 4, 256, 0, stream>>>(c3pb, slb, garw, garb,
                                           (float*)d_out);
}

// Round 20
// 113.884 us; speedup vs baseline: 1.0318x; 1.0318x over previous
//
#include <hip/hip_runtime.h>
#include <hip/hip_bf16.h>

#define B 16
#define T 128
#define D 256
#define H 64
#define C1 64
#define C2 20
#define K2 4096   // H*C1
#define F2 1280   // H*C2
#define OUTW 32
#define ALPHA 0.2f

typedef __attribute__((ext_vector_type(8))) short short8;
typedef __attribute__((ext_vector_type(4))) float f32x4;

static __device__ __forceinline__ ushort f2bf(float f) {
    __hip_bfloat16 h = __float2bfloat16(f);
    return *reinterpret_cast<ushort*>(&h);
}
static __device__ __forceinline__ float bf2f(ushort u) {
    return __uint_as_float(((unsigned int)u) << 16);
}
// async global->LDS, 16B per lane; LDS dest is wave-uniform base + lane*16.
static __device__ __forceinline__ void gload16(const ushort* g, ushort* l) {
    __builtin_amdgcn_global_load_lds((const unsigned int*)g, (unsigned int*)l,
                                     16, 0, 0);
}

// ---------------------------------------------------------------------------
// Split-K MFMA GEMM (verified round 8) + PERM epilogue (verified round 11).
// ---------------------------------------------------------------------------
template<int KD, int NBLK, int MBLK, int KSPLIT, int PERM>
__global__ __launch_bounds__(256) void gemm_splitk_kernel(
    const ushort* __restrict__ Ag, const ushort* __restrict__ Bg,
    ushort* __restrict__ Cp)
{
    __shared__ ushort As[128 * 64];
    __shared__ ushort Bs[128 * 64];
    constexpr int NN = NBLK * 128;
    constexpr int MM = MBLK * 128;
    constexpr int NT = MBLK * NBLK;
    constexpr int TOTAL = NT * KSPLIT;
    constexpr int KDP = KD / KSPLIT;
    static_assert(TOTAL % 8 == 0, "swizzle needs multiple of 8 blocks");
    static_assert(KDP % 64 == 0, "K partition must be a multiple of BK=64");

    int tid = threadIdx.x;
    int bid = blockIdx.x;
    int wg = (bid & 7) * (TOTAL / 8) + (bid >> 3);
    int kp = wg / NT; int tile = wg - kp * NT;
    int bm = (tile / NBLK) * 128, bn = (tile % NBLK) * 128;

    int wave = tid >> 6, lane = tid & 63;
    int wm = (wave >> 1) * 64, wn = (wave & 1) * 64;
    int lr = lane & 15, lk = lane >> 4;
    int srow = lane >> 3, scol = (lane & 7) * 8;

    f32x4 acc[4][4];
    #pragma unroll
    for (int i = 0; i < 4; ++i)
        #pragma unroll
        for (int j = 0; j < 4; ++j) acc[i][j] = (f32x4){0.f, 0.f, 0.f, 0.f};

    const ushort* ApB = Ag + (size_t)bm * KD + kp * KDP;
    const ushort* BpB = Bg + (size_t)bn * KD + kp * KDP;

    for (int k0 = 0; k0 < KDP; k0 += 64) {
        __syncthreads();
        #pragma unroll
        for (int e = 0; e < 4; ++e) {
            int c = e * 4 + wave;
            gload16(ApB + (size_t)(8 * c + srow) * KD + k0 + scol, &As[c * 512]);
            gload16(BpB + (size_t)(8 * c + srow) * KD + k0 + scol, &Bs[c * 512]);
        }
        __syncthreads();
        #pragma unroll
        for (int ks = 0; ks < 2; ++ks) {
            short8 af[4], bfr[4];
            #pragma unroll
            for (int i = 0; i < 4; ++i)
                af[i] = *(const short8*)&As[(wm + i * 16 + lr) * 64 + ks * 32 + lk * 8];
            #pragma unroll
            for (int j = 0; j < 4; ++j)
                bfr[j] = *(const short8*)&Bs[(wn + j * 16 + lr) * 64 + ks * 32 + lk * 8];
            #pragma unroll
            for (int i = 0; i < 4; ++i)
                #pragma unroll
                for (int j = 0; j < 4; ++j)
                    acc[i][j] = __builtin_amdgcn_mfma_f32_16x16x32_bf16(
                        af[i], bfr[j], acc[i][j], 0, 0, 0);
        }
    }

    if constexpr (PERM) {
        ushort* Cw = Cp + (size_t)kp * MM * NN + (size_t)tile * 16384
                   + wave * 4096 + lane * 4;
        #pragma unroll
        for (int i = 0; i < 4; ++i)
            #pragma unroll
            for (int j = 0; j < 4; ++j) {
                union { ushort q[4]; uint2 v; } pk;
                #pragma unroll
                for (int r = 0; r < 4; ++r) pk.q[r] = f2bf(acc[i][j][r]);
                *(uint2*)&Cw[(i * 4 + j) * 256] = pk.v;
            }
    } else {
        ushort* Cout = Cp + (size_t)kp * MM * NN;
        #pragma unroll
        for (int i = 0; i < 4; ++i) {
            #pragma unroll
            for (int j = 0; j < 4; ++j) {
                int col = bn + wn + j * 16 + lr;
                #pragma unroll
                for (int r = 0; r < 4; ++r) {
                    int row = bm + wm + i * 16 + lk * 4 + r;
                    Cout[(size_t)row * NN + col] = f2bf(acc[i][j][r]);
                }
            }
        }
    }
}

// ---------------------------------------------------------------------------
// FUSED kernel 1 v5: v4 + whT/CT LDS UNION (whT dead before barrier 3; CT
// first written after). LDS 37.4KB -> 20.0KB => residency 4 -> ~6 blocks/CU.
// ---------------------------------------------------------------------------
#define WHT_(r,c) u1.whT[(r) * 136 + (c)]

__global__ __launch_bounds__(256) void fused1_kernel(
    const ushort* __restrict__ xbf,   // [B*T][256] bf16
    const ushort* __restrict__ w1t,   // [H*64][256] bf16
    const float* __restrict__ b1,     // [4096] ([h][c] flat)
    const float* __restrict__ a1s, const float* __restrict__ a1d,
    const float* __restrict__ a1b,
    ushort* __restrict__ c1)          // [B*T][4096] row-major
{
    int blk = blockIdx.x; int b = blk >> 6, h = blk & 63;
    __shared__ union {
        ushort whT[64 * 136];          // phases A..D
        ushort CT[128 * 72];           // epilogue (after barrier 3)
    } u1;
    __shared__ float ss[128], ddv[128], sinv[128];

    int tid = threadIdx.x;
    int wave = tid >> 6, lane = tid & 63;
    int wm2 = wave * 32;
    int lr = lane & 15, lk = lane >> 4;

    // ---- phase A: Wh1 = x @ w1t^T, fragment-direct global loads ----
    f32x4 acc[2][4];
    #pragma unroll
    for (int i = 0; i < 2; ++i)
        #pragma unroll
        for (int j = 0; j < 4; ++j) acc[i][j] = (f32x4){0.f, 0.f, 0.f, 0.f};

    const ushort* Abase = xbf + (size_t)(b * T + wm2 + lr) * D + lk * 8;
    const ushort* Bbase = w1t + (size_t)(h * 64 + lr) * D + lk * 8;

    #pragma unroll 2
    for (int kb = 0; kb < 8; ++kb) {
        short8 af[2], bfr[4];
        #pragma unroll
        for (int i = 0; i < 2; ++i)
            af[i] = *(const short8*)(Abase + (size_t)i * 16 * D + kb * 32);
        #pragma unroll
        for (int j = 0; j < 4; ++j)
            bfr[j] = *(const short8*)(Bbase + (size_t)j * 16 * D + kb * 32);
        #pragma unroll
        for (int i = 0; i < 2; ++i)
            #pragma unroll
            for (int j = 0; j < 4; ++j)
                acc[i][j] = __builtin_amdgcn_mfma_f32_16x16x32_bf16(
                    af[i], bfr[j], acc[i][j], 0, 0, 0);
    }

    // epilogue: whT[col][t] = bf16(Wh + bias)
    #pragma unroll
    for (int j = 0; j < 4; ++j) {
        int col = j * 16 + lr;
        float bv = b1[h * C1 + col];
        #pragma unroll
        for (int i = 0; i < 2; ++i) {
            int t0 = wm2 + i * 16 + lk * 4;
            union { ushort q[4]; uint2 v; } pk;
            #pragma unroll
            for (int r = 0; r < 4; ++r) pk.q[r] = f2bf(acc[i][j][r] + bv);
            *(uint2*)&WHT_(col, t0) = pk.v;
        }
    }
    __syncthreads();                                   // barrier 1

    // ---- phase B: scores ----
    {
        int t = tid & 127;
        bool isS = tid < 128;
        const float* av = (isS ? a1s : a1d) + h * C1;
        float s = isS ? a1b[h] : 0.f;
        #pragma unroll 8
        for (int c = 0; c < 64; ++c) s = fmaf(bf2f(WHT_(c, t)), av[c], s);
        if (isS) ss[t] = s; else ddv[t] = s;
    }
    __syncthreads();                                   // barrier 2

    // ---- phase C'+D: P~ in-register + PV MFMA ----
    float dm = fmaxf(ddv[lane], ddv[lane + 64]);
    #pragma unroll
    for (int msk = 1; msk < 64; msk <<= 1) dm = fmaxf(dm, __shfl_xor(dm, msk));

    float si[2], mi[2], rsum[2];
    #pragma unroll
    for (int i = 0; i < 2; ++i) {
        si[i] = ss[wm2 + i * 16 + lr];
        float mx = si[i] + dm;
        mi[i] = mx >= 0.f ? mx : ALPHA * mx;
        rsum[i] = 0.f;
    }

    f32x4 acc2[2][4];
    #pragma unroll
    for (int i = 0; i < 2; ++i)
        #pragma unroll
        for (int j = 0; j < 4; ++j) acc2[i][j] = (f32x4){0.f, 0.f, 0.f, 0.f};

    #pragma unroll
    for (int ks = 0; ks < 4; ++ks) {
        float dj[8];
        #pragma unroll
        for (int e = 0; e < 8; ++e) dj[e] = ddv[ks * 32 + lk * 8 + e];
        short8 bfr[4];
        #pragma unroll
        for (int j = 0; j < 4; ++j)
            bfr[j] = *(const short8*)&WHT_(j * 16 + lr, ks * 32 + lk * 8);
        #pragma unroll
        for (int i = 0; i < 2; ++i) {
            union { ushort q[8]; short8 s; } pk;
            #pragma unroll
            for (int e = 0; e < 8; ++e) {
                float ee = si[i] + dj[e];
                ee = ee >= 0.f ? ee : ALPHA * ee;
                float pp = __expf(ee - mi[i]);
                rsum[i] += pp;
                pk.q[e] = f2bf(pp);
            }
            #pragma unroll
            for (int j = 0; j < 4; ++j)
                acc2[i][j] = __builtin_amdgcn_mfma_f32_16x16x32_bf16(
                    pk.s, bfr[j], acc2[i][j], 0, 0, 0);
        }
    }

    #pragma unroll
    for (int i = 0; i < 2; ++i) {
        rsum[i] += __shfl_xor(rsum[i], 16);
        rsum[i] += __shfl_xor(rsum[i], 32);
    }
    if (lk == 0) {
        #pragma unroll
        for (int i = 0; i < 2; ++i) sinv[wm2 + i * 16 + lr] = 1.0f / rsum[i];
    }
    __syncthreads();                                   // barrier 3 (whT dead)

    // ---- epilogue: CT restage (aliases whT), then coalesced uint4 rows ----
    #pragma unroll
    for (int i = 0; i < 2; ++i) {
        #pragma unroll
        for (int r = 0; r < 4; ++r) {
            int row = wm2 + i * 16 + lk * 4 + r;
            float sv = sinv[row];
            #pragma unroll
            for (int j = 0; j < 4; ++j) {
                int col = j * 16 + lr;
                float v = acc2[i][j][r] * sv;
                v = v > 0.f ? v : 0.f;
                v = 1.0f / (1.0f + __expf(-v));
                u1.CT[row * 72 + col] = f2bf(v);
            }
        }
    }
    __syncthreads();                                   // barrier 4
    #pragma unroll
    for (int e = 0; e < 4; ++e) {
        int idx = e * 256 + tid;           // 0..1023: row = idx>>3, q = idx&7
        int row = idx >> 3, q = idx & 7;
        uint4 v = *(const uint4*)&u1.CT[row * 72 + q * 8];
        *(uint4*)&c1[((size_t)(b * T + row)) * K2 + h * C1 + q * 8] = v;
    }
}

// ---------------------------------------------------------------------------
// FUSED kernel 2 (round 17 verified): vectorized split-K gather over 8
// partials -> scores -> P~ -> PV MFMA -> coalesced c2 write.
// ---------------------------------------------------------------------------
#define PB2_(r,c)  Pb2[(r) * 136 + (c)]
#define WHT2_(r,c) whT2[(r) * 136 + (c)]

__global__ __launch_bounds__(256) void fused2_kernel(
    const ushort* __restrict__ wh2pb,  // [8] x permuted [2048][1280] bf16
    const float* __restrict__ b2,      // [1280] ([h][c] flat)
    const float* __restrict__ a2s, const float* __restrict__ a2d,
    const float* __restrict__ a2b,
    ushort* __restrict__ c2)
{
    int blk = blockIdx.x; int b = blk >> 6, h = blk & 63;
    __shared__ ushort Pb2[128 * 136];
    __shared__ ushort whT2[32 * 136];
    __shared__ float ss[128], ddv[128], sinv[128];

    int tid = threadIdx.x;
    int wave = tid >> 6, lane = tid & 63;
    int lr = lane & 15, lk = lane >> 4;
    const size_t MNfull = (size_t)2048 * F2;

    // ---- load + split-K reduce: 640 (t-quad, c) tasks, uint2 per partial ----
    for (int e = 0; e < 3; ++e) {
        int idx = e * 256 + tid;
        if (idx < 640) {
            int tq = idx / 20, c = idx - tq * 20;
            int col = h * C2 + c;
            int tn = col >> 7, cl = col & 127;
            int fj = (cl >> 4) & 3, fl = cl & 15;
            int t0 = tq * 4;
            int wv = ((t0 >> 6) << 1) | (cl >> 6);
            int fi = (t0 >> 4) & 3, fk = (t0 >> 2) & 3;
            size_t fa = (size_t)(b * 10 + tn) * 16384 + wv * 4096
                      + (fi * 4 + fj) * 256 + (fk * 16 + fl) * 4;
            float bv = b2[col];
            float s0 = bv, s1 = bv, s2 = bv, s3 = bv;
            #pragma unroll
            for (int p = 0; p < 8; ++p) {
                uint2 v = *(const uint2*)&wh2pb[p * MNfull + fa];
                s0 += bf2f((ushort)(v.x & 0xffff));
                s1 += bf2f((ushort)(v.x >> 16));
                s2 += bf2f((ushort)(v.y & 0xffff));
                s3 += bf2f((ushort)(v.y >> 16));
            }
            union { ushort q[4]; uint2 u; } o;
            o.q[0] = f2bf(s0); o.q[1] = f2bf(s1);
            o.q[2] = f2bf(s2); o.q[3] = f2bf(s3);
            *(uint2*)&WHT2_(c, t0) = o.u;
        }
    }
    {   // zero-pad rows 20..31
        int idx = tid;
        for (int e = 0; e < 6; ++e, idx += 256) {
            int c = 20 + (idx >> 7), t = idx & 127;
            WHT2_(c, t) = 0;
        }
    }
    __syncthreads();

    // ---- scores ----
    {
        int t = tid & 127;
        bool isS = tid < 128;
        const float* av = (isS ? a2s : a2d) + h * C2;
        float s = isS ? a2b[h] : 0.f;
        #pragma unroll
        for (int c = 0; c < 20; ++c) s = fmaf(bf2f(WHT2_(c, t)), av[c], s);
        if (isS) ss[t] = s; else ddv[t] = s;
    }
    __syncthreads();

    // ---- P~ + row sums ----
    {
        float dm = fmaxf(ddv[lane], ddv[lane + 64]);
        #pragma unroll
        for (int msk = 1; msk < 64; msk <<= 1) dm = fmaxf(dm, __shfl_xor(dm, msk));
        int i = tid >> 1, j0 = (tid & 1) * 64;
        float si = ss[i];
        float mx = si + dm; mx = mx >= 0.f ? mx : ALPHA * mx;
        float lsum = 0.f;
        #pragma unroll
        for (int g = 0; g < 8; ++g) {
            union { ushort q[8]; uint4 v; } pk;
            #pragma unroll
            for (int e = 0; e < 8; ++e) {
                float ee = si + ddv[j0 + g * 8 + e];
                ee = ee >= 0.f ? ee : ALPHA * ee;
                float pp = __expf(ee - mx);
                lsum += pp;
                pk.q[e] = f2bf(pp);
            }
            *(uint4*)&PB2_(i, j0 + g * 8) = pk.v;
        }
        lsum += __shfl_xor(lsum, 1);
        if (!(tid & 1)) sinv[i] = 1.0f / lsum;
    }
    __syncthreads();

    // ---- PV: out[128][32] = P~ @ whT2^T; wave owns 32 rows ----
    int wm2 = wave * 32;
    f32x4 acc2[2][2];
    #pragma unroll
    for (int i = 0; i < 2; ++i)
        #pragma unroll
        for (int j = 0; j < 2; ++j) acc2[i][j] = (f32x4){0.f, 0.f, 0.f, 0.f};

    #pragma unroll
    for (int ks = 0; ks < 4; ++ks) {
        short8 af[2], bfr[2];
        #pragma unroll
        for (int i = 0; i < 2; ++i)
            af[i] = *(const short8*)&PB2_(wm2 + i * 16 + lr, ks * 32 + lk * 8);
        #pragma unroll
        for (int j = 0; j < 2; ++j)
            bfr[j] = *(const short8*)&WHT2_(j * 16 + lr, ks * 32 + lk * 8);
        #pragma unroll
        for (int i = 0; i < 2; ++i)
            #pragma unroll
            for (int j = 0; j < 2; ++j)
                acc2[i][j] = __builtin_amdgcn_mfma_f32_16x16x32_bf16(
                    af[i], bfr[j], acc2[i][j], 0, 0, 0);
    }

    // ---- coalesced epilogue via LDS restage (reuse Pb2) ----
    __syncthreads();
    ushort* CT2 = Pb2;                     // [128][24]
    #pragma unroll
    for (int i = 0; i < 2; ++i) {
        #pragma unroll
        for (int r = 0; r < 4; ++r) {
            int row = wm2 + i * 16 + lk * 4 + r;
            float sv = sinv[row];
            #pragma unroll
            for (int j = 0; j < 2; ++j) {
                int col = j * 16 + lr;
                if (col < C2) {
                    float v = acc2[i][j][r] * sv;
                    v = v > 0.f ? v : 0.f;
                    v = 1.0f / (1.0f + __expf(-v));
                    CT2[row * 24 + col] = f2bf(v);
                }
            }
        }
    }
    __syncthreads();
    for (int e = 0; e < 3; ++e) {
        int idx = e * 256 + tid;           // 0..639: row = idx/5, q = idx%5
        if (idx < 640) {
            int row = idx / 5, q = idx - row * 5;
            uint2 v = *(const uint2*)&CT2[row * 24 + q * 4];
            *(uint2*)&c2[((size_t)(b * T + row)) * F2 + h * C2 + q * 4] = v;
        }
    }
}

// ---------------------------------------------------------------------------
// MERGED prep kernel (verified round 17).
// ---------------------------------------------------------------------------
__global__ __launch_bounds__(256) void prep_kernel(
    const float* __restrict__ x,  const float* __restrict__ W1,
    const float* __restrict__ W2, const float* __restrict__ slw,
    ushort* __restrict__ xbf, ushort* __restrict__ w1t,
    ushort* __restrict__ w2t, ushort* __restrict__ slwt)
{
    __shared__ union { float a[64][65]; float b[128][21]; } lw;
    int bid = blockIdx.x, tid = threadIdx.x;

    if (bid < 512) {                       // ---- xbf ----
        int i = bid * 256 + tid;
        float4 v = *(const float4*)&x[(size_t)i * 4];
        union { ushort u[4]; uint2 p; } o;
        o.u[0] = f2bf(v.x); o.u[1] = f2bf(v.y);
        o.u[2] = f2bf(v.z); o.u[3] = f2bf(v.w);
        *(uint2*)&xbf[(size_t)i * 4] = o.p;
    } else if (bid < 768) {                // ---- w1t ----
        int blk = bid - 512; int h = blk >> 2, d0 = (blk & 3) * 64;
        for (int e = 0; e < 16; ++e) {
            int idx = e * 256 + tid; int dr = idx >> 6, c = idx & 63;
            lw.a[dr][c] = W1[((size_t)h * D + d0 + dr) * C1 + c];
        }
        __syncthreads();
        for (int e = 0; e < 16; ++e) {
            int idx = e * 256 + tid; int c = idx >> 6, dr = idx & 63;
            w1t[((size_t)(h * 64 + c)) * D + d0 + dr] = f2bf(lw.a[dr][c]);
        }
    } else if (bid < 2816) {               // ---- w2t ----
        int blk = bid - 768; int h = blk >> 5, kb = blk & 31; int k0 = kb * 128;
        const float* src = W2 + ((size_t)h * K2 + k0) * C2;
        for (int e = 0; e < 10; ++e) {
            int idx = e * 256 + tid; int k = idx / 20, c = idx - k * 20;
            lw.b[k][c] = src[idx];
        }
        __syncthreads();
        for (int e = 0; e < 10; ++e) {
            int idx = e * 256 + tid; int c = idx >> 7, k = idx & 127;
            w2t[((size_t)(h * 20 + c)) * K2 + k0 + k] = f2bf(lw.b[k][c]);
        }
    } else {                               // ---- slwt ----
        int blk = bid - 2816; int kb = blk >> 2, d0 = (blk & 3) * 64;
        int k0 = kb * 64;
        for (int e = 0; e < 16; ++e) {
            int idx = e * 256 + tid; int kr = idx >> 6, dc = idx & 63;
            lw.a[kr][dc] = slw[((size_t)(k0 + kr)) * D + d0 + dc];
        }
        __syncthreads();
        for (int e = 0; e < 16; ++e) {
            int idx = e * 256 + tid; int dr = idx >> 6, kc = idx & 63;
            slwt[((size_t)(d0 + dr)) * F2 + k0 + kc] = f2bf(lw.a[kc][dr]);
        }
    }
}

// ---------------------------------------------------------------------------
// MERGED gar2 (verified round 17): reduce 4 sl-partials (+slb), then GAR.
// ---------------------------------------------------------------------------
__global__ __launch_bounds__(256) void gar2_kernel(
    const ushort* __restrict__ c3pb,   // [4][2048][256] bf16 partials
    const float* __restrict__ slb, const float* __restrict__ garw,
    const float* __restrict__ garb, float* __restrict__ out)
{
    int blk = blockIdx.x; int b = blk >> 2, dt = (blk & 3) * 64;
    __shared__ float cs[128][65];
    __shared__ float gw[128][32];
    int tid = threadIdx.x;

    for (int e = 0; e < 32; ++e) {
        int idx = e * 256 + tid;
        int t = idx >> 6, d = idx & 63;
        size_t off = (size_t)(b * T + t) * D + dt + d;
        float s = slb[dt + d];
        #pragma unroll
        for (int p = 0; p < 4; ++p)
            s += bf2f(c3pb[(size_t)p * 2048 * 256 + off]);
        cs[t][d] = s;
    }
    for (int e = 0; e < 16; ++e) {
        int idx = e * 256 + tid;
        int t = idx >> 5, o = idx & 31;
        gw[t][o] = garw[t * OUTW + o];
    }
    __syncthreads();

    int d = tid & 63, o0 = (tid >> 6) * 8;
    float accv[8];
    #pragma unroll
    for (int q = 0; q < 8; ++q) accv[q] = garb[o0 + q];
    for (int t = 0; t < T; ++t) {
        float cv = cs[t][d];
        #pragma unroll
        for (int q = 0; q < 8; ++q) accv[q] = fmaf(cv, gw[t][o0 + q], accv[q]);
    }
    #pragma unroll
    for (int q = 0; q < 8; ++q)
        out[((size_t)b * OUTW + o0 + q) * D + dt + d] = accv[q];
}

// ---------------------------------------------------------------------------
extern "C" void kernel_launch(void* const* d_in, const int* in_sizes, int n_in,
                              void* d_out, int out_size, void* d_ws, size_t ws_size,
                              hipStream_t stream) {
    const float* x    = (const float*)d_in[0];
    const float* W1   = (const float*)d_in[1];
    const float* b1   = (const float*)d_in[2];
    const float* a1s  = (const float*)d_in[3];
    const float* a1d  = (const float*)d_in[4];
    const float* a1b  = (const float*)d_in[5];
    const float* W2   = (const float*)d_in[6];
    const float* b2   = (const float*)d_in[7];
    const float* a2s  = (const float*)d_in[8];
    const float* a2d  = (const float*)d_in[9];
    const float* a2b  = (const float*)d_in[10];
    const float* slw  = (const float*)d_in[11];
    const float* slb  = (const float*)d_in[12];
    const float* garw = (const float*)d_in[13];
    const float* garb = (const float*)d_in[14];

    char* p = (char*)d_ws;
    ushort* xbf   = (ushort*)p;  p += (size_t)2048 * 256  * 2;     //  1.0 MB
    ushort* w1t   = (ushort*)p;  p += (size_t)4096 * 256  * 2;     //  2.1 MB
    ushort* c1bf  = (ushort*)p;  p += (size_t)2048 * 4096 * 2;     // 16.8 MB
    ushort* w2t   = (ushort*)p;  p += (size_t)1280 * 4096 * 2;     // 10.5 MB
    ushort* c2bf  = (ushort*)p;  p += (size_t)2048 * 1280 * 2;     //  5.2 MB
    ushort* slwt  = (ushort*)p;  p += (size_t)256  * 1280 * 2;     //  0.7 MB
    ushort* wh2pb = (ushort*)p;  p += (size_t)8 * 2048 * 1280 * 2; // 42 MB
    ushort* c3pb  = (ushort*)c1bf;   // aliases c1bf (dead after gemm2 reads it)
    // c3pb needs 4*2048*256*2 = 4.2 MB <= c1bf's 16.8 MB ✓

    prep_kernel<<<2896, 256, 0, stream>>>(x, W1, W2, slw, xbf, w1t, w2t, slwt);

    fused1_kernel<<<B * H, 256, 0, stream>>>(xbf, w1t, b1, a1s, a1d, a1b, c1bf);

    gemm_splitk_kernel<4096, 10, 16, 8, 1><<<1280, 256, 0, stream>>>(c1bf, w2t,
                                                                     wh2pb);
    fused2_kernel<<<B * H, 256, 0, stream>>>(wh2pb, b2, a2s, a2d, a2b, c2bf);

    gemm_splitk_kernel<1280, 2, 16, 4, 0><<<128, 256, 0, stream>>>(c2bf, slwt,
                                                                   c3pb);
    gar2_kernel<<<B * 4, 256, 0, stream>>>(c3pb, slb, garw, garb,
                                           (float*)d_out);
}